// Round 12
// baseline (388.566 us; speedup 1.0000x reference)
//
#include <hip/hip_runtime.h>

// SRLoss: loss = mean((inp - avgpool10x10(output))^2) + BCE(output, target)
// output/target: [32,1,1280,1280] f32; inp: [32,1,128,128] f32; out: scalar f32.
//
// R15 post-mortem: 640-thread blocks under nt = null (374.8 vs 376.5us).
// Confound: compiler sank the register preload again (28 VGPR) -> R15 varied
// waves, not in-flight bytes. Post-nt arithmetic: 4.0 TB/s read = ~14KB in
// flight/CU at ~900ns; fills do 6.8 TB/s -> not a wall. The only proven
// issue-width forcer is global_load_lds (R12: 10 stages/wave back-to-back,
// zero VGPR dests), which was null pre-nt only because the L3-thrash cap
// (removed by R14's nt) sat below it.
// R16: R12's staging kernel + aux=2 (NT bit, gfx940+ CPol: SC0=1,NT=2,SC1=16)
// on every global_load_lds. Combines both proven mechanisms: forced 10KB/wave
// in flight x L3 bypass. Correctness inherited from R12 (passed bit-exact).
// Pre-commit: partial -> 70-85us (bench ~340-355) = in-flight was the
// limiter. Unchanged ~375 = ~4 TB/s is this pattern's ceiling -> ROOFLINE.
// >390 = staging overhead dominates under nt -> revert to R14 as final.

#define BATCH 32
#define HH 1280
#define WW 1280
#define PH 128
#define PW 128
#define SC 10
#define NT 320                      // threads per block (5 waves)
#define RPC 5                       // rows staged per chunk
#define NCH 2                       // chunks per band (RPC*NCH = SC)
#define NB (BATCH * PH)             // 4096 bands = 4096 blocks
#define NT2 512                     // reduce-kernel threads

static constexpr float EPSV = 1e-20f;
static constexpr float LN2  = 0.6931471805599453f;
static constexpr float INV_NBCE = 1.0f / (float)(BATCH * HH * WW);   // bce mean
static constexpr float INV_NM   = 1.0f / (float)(BATCH * PH * PW);   // mse mean

// Async global->LDS, 16B per lane, NT cache policy (aux=2: bypass/stream L3).
#define STAGE16NT(gp, lp)                                                 \
    __builtin_amdgcn_global_load_lds(                                     \
        (const __attribute__((address_space(1))) void*)(const void*)(gp), \
        (__attribute__((address_space(3))) void*)(void*)(lp), 16, 0, 2)

__global__ __launch_bounds__(NT, 4) void srloss_partial(
    const float* __restrict__ output,
    const float* __restrict__ target,
    const float* __restrict__ inp,
    float* __restrict__ partials)
{
    __shared__ float so[RPC * WW];  // 5 rows of output: 25,600 B
    __shared__ float st[RPC * WW];  // 5 rows of target: 25,600 B
    __shared__ float psum[PW];      // pooled column sums for this band
    __shared__ float red[NT / 64];  // cross-wave reduction scratch

    const int t = threadIdx.x;
    const int band = blockIdx.x;    // 0 .. BATCH*PH-1
    const int b = band >> 7;        // band / 128
    const int pr = band & 127;      // band % 128

    if (t < PW) psum[t] = 0.0f;

    const size_t base = ((size_t)b * HH + (size_t)pr * SC) * WW;
    const float* op = output + base + 4 * t;   // per-lane global src, row 0
    const float* tp = target + base + 4 * t;

    // LDS dest: wave-uniform base; HW adds lane*16. Wave w of row r covers
    // bytes [w*1024,(w+1)*1024) -> lane lands exactly at float 4t of the row.
    const int wbase = (t >> 6) << 8;           // wave_id * 256 floats

    // c = 4t for every row -> pooled-column mapping is row-invariant
    const int col0 = 4 * t;
    const int p0 = col0 / SC;
    const bool straddle = (col0 % SC) == 8;    // o[2],o[3] belong to p0+1

    float acc2 = 0.0f;              // sum log2(oc)
    float accd = 0.0f;              // sum t*(log2(om)-log2(oc))
    float s0 = 0.0f, s1 = 0.0f;     // pooled sums: halves of the float4

    #pragma unroll
    for (int h = 0; h < NCH; ++h) {
        __syncthreads();            // guard LDS buffer reuse (h=0: psum init)

        // issue all 10 stages back-to-back: 10 KB in flight per wave,
        // zero VGPR destinations -> compiler cannot collapse this.
        #pragma unroll
        for (int r = 0; r < RPC; ++r) {
            const int row = h * RPC + r;
            STAGE16NT(op + (size_t)row * WW, &so[r * WW + wbase]);
            STAGE16NT(tp + (size_t)row * WW, &st[r * WW + wbase]);
        }
        __syncthreads();            // compiler emits s_waitcnt vmcnt(0)
                                    // before s_barrier -> staged data ready

        #pragma unroll
        for (int r = 0; r < RPC; ++r) {
            const float4 o4 = *(const float4*)&so[r * WW + 4 * t];
            const float4 t4 = *(const float4*)&st[r * WW + 4 * t];
            const float o[4]  = {o4.x, o4.y, o4.z, o4.w};
            const float tg[4] = {t4.x, t4.y, t4.z, t4.w};
            #pragma unroll
            for (int j = 0; j < 4; ++j) {
                const float om = fmaxf(o[j], EPSV);
                const float oc = fmaxf(1.0f - o[j], EPSV);
                const float l1 = __log2f(om);
                const float l2 = __log2f(oc);
                acc2 += l2;
                accd += tg[j] * (l1 - l2);
            }
            s0 += o[0] + o[1];
            s1 += o[2] + o[3];
        }
    }
    const float bce_acc = LN2 * (acc2 + accd);

    if (straddle) {
        atomicAdd(&psum[p0],     s0);
        atomicAdd(&psum[p0 + 1], s1);
    } else {
        atomicAdd(&psum[p0], s0 + s1);
    }
    __syncthreads();

    // MSE terms: one pooled element per thread for t < 128
    float mse_acc = 0.0f;
    if (t < PW) {
        const float pooled = psum[t] * (1.0f / (float)(SC * SC));
        const float iv = inp[(size_t)band * PW + t];
        const float d = iv - pooled;
        mse_acc = d * d;
    }

    // per-block contribution, pre-normalized
    float contrib = (-INV_NBCE) * bce_acc + INV_NM * mse_acc;

    #pragma unroll
    for (int off = 32; off > 0; off >>= 1)
        contrib += __shfl_down(contrib, off, 64);
    if ((t & 63) == 0) red[t >> 6] = contrib;
    __syncthreads();

    // plain store to a distinct slot: no RMW chain, no fence
    if (t == 0) {
        float s = 0.0f;
        #pragma unroll
        for (int w = 0; w < NT / 64; ++w) s += red[w];
        partials[band] = s;
    }
}

__global__ __launch_bounds__(NT2) void srloss_reduce(
    const float* __restrict__ partials,
    float* __restrict__ out)
{
    __shared__ float red[NT2 / 64];
    const int t = threadIdx.x;

    // 4096 floats = 1024 float4; 512 threads x 2 float4 each
    const float4 v0 = ((const float4*)partials)[t];
    const float4 v1 = ((const float4*)partials)[t + NT2];
    float s = (v0.x + v0.y) + (v0.z + v0.w) + (v1.x + v1.y) + (v1.z + v1.w);

    #pragma unroll
    for (int off = 32; off > 0; off >>= 1)
        s += __shfl_down(s, off, 64);
    if ((t & 63) == 0) red[t >> 6] = s;
    __syncthreads();
    if (t == 0) {
        float tot = 0.0f;
        #pragma unroll
        for (int w = 0; w < NT2 / 64; ++w) tot += red[w];
        out[0] = tot;
    }
}

extern "C" void kernel_launch(void* const* d_in, const int* in_sizes, int n_in,
                              void* d_out, int out_size, void* d_ws, size_t ws_size,
                              hipStream_t stream) {
    const float* output = (const float*)d_in[0];
    const float* target = (const float*)d_in[1];
    const float* inp    = (const float*)d_in[2];
    float* out = (float*)d_out;
    float* partials = (float*)d_ws;              // 4096 floats = 16 KB

    srloss_partial<<<NB, NT, 0, stream>>>(output, target, inp, partials);
    srloss_reduce<<<1, NT2, 0, stream>>>(partials, out);
}